// Round 2
// baseline (153.236 us; speedup 1.0000x reference)
//
#include <hip/hip_runtime.h>
#include <hip/hip_bf16.h>

// RecursiveNN, perfect binary tree. N=262144 leaves, IN=64, HID=128.
// SETTLED: inputs fp32 jax-layout ([K,N] weights), output fp32[128].
// R10: 168.4us. R11: 142.0us (kprep prestaged frags, tanh-scale fold,
//   bias-in-acc, VGPR 68) -- but kfront occupancy stuck at 2 blocks/CU
//   (LDS 53248*3 = 159744 right at the 160KB edge), 45us issue-bound.
// R12 (this):
//  - kfront 64-leaf blocks (4096): LDS 26624 B -> 6 blocks/CU (3x packing).
//  - l1/l2 intermediates stored bf16 (numerically identical: values passed
//    through bf16 LDS anyway); kmid/tail gathers are uint4, zero cvt.
//  - ktail merged into kmid via last-block (threadfence+atomic) pattern.
//  - XB never written in ws-mode (all scratch in d_ws, 4.3MB); fallback to
//    XB scratch + separate ktail if ws_size too small.
// Level split: kfront 1..4 (16384 rows), kmid 5..11 (128 rows), tail 12..18.
// H LDS: row stride 136 bf16, col swizzle c ^ (((row>>3)&3)<<3).

typedef unsigned short u16;
typedef unsigned int u32;
typedef __attribute__((ext_vector_type(8))) short bf16x8;   // 8 bf16, 4 VGPR
typedef __attribute__((ext_vector_type(4))) float f32x4;

#define TANH_S 2.8853900817779268f  // 2/ln2; tanh(x) = 1 - 2/(exp2(S*x)+1)

__device__ __forceinline__ u16 f2bf(float f) {
    __hip_bfloat16 h = __float2bfloat16(f);   // RNE
    return *(u16*)&h;
}
__device__ __forceinline__ u32 f2bf_pk(float a, float b) {
    __hip_bfloat162 h = __float22bfloat162_rn(make_float2(a, b));
    return *(u32*)&h;
}
// NaN-free tanh, input PRE-SCALED by TANH_S (scale folded into weights/bias)
__device__ __forceinline__ float tanh_ps(float xs) {
#if __has_builtin(__builtin_amdgcn_exp2f) && __has_builtin(__builtin_amdgcn_rcpf)
    float t = __builtin_amdgcn_exp2f(xs);
    float r = __builtin_amdgcn_rcpf(t + 1.0f);
    return __builtin_fmaf(-2.0f, r, 1.0f);
#else
    float e = __expf(xs * 0.6931471805599453f);
    return 1.0f - 2.0f / (e + 1.0f);
#endif
}
__device__ __forceinline__ int swz(int row, int c) {
    return c ^ (((row >> 3) & 3) << 3);
}

#define MFMA16(a, b, c) __builtin_amdgcn_mfma_f32_16x16x32_bf16((a), (b), (c), 0, 0, 0)

// ---- d_ws layout ------------------------------------------------------------
// frags (u16): bw slot s=kc*2+i (16 slots) at ws[s*2048 + tid*8];
//              bwin (4 slots) at ws[32768 + s*2048 + tid*8].  81920 B total.
// L1OUT  bf16 [16384][128] at byte 81920            (4194304 B)
// L2OUT  bf16 [128][128]   at byte 4276224          (32768 B)
// counter u32              at byte 4308992
#define WS_BWIN 32768
#define WS_L1_BYTE 81920
#define WS_L2_BYTE (WS_L1_BYTE + 4194304)
#define WS_CNT_BYTE (WS_L2_BYTE + 32768)
#define WS_NEED (WS_CNT_BYTE + 64)

// ---- kprep: materialize bf16 B-frags (scaled by TANH_S) into d_ws ----------
__global__ __launch_bounds__(256) void kprep(
    const float* __restrict__ Win, const float* __restrict__ Wl,
    const float* __restrict__ Wr, u16* __restrict__ ws, u32* counter) {
    const int tid = threadIdx.x;
    const int w = tid >> 6, lane = tid & 63, quad = lane >> 4, lq = lane & 15;
    const int c0 = 32 * w + 2 * lq;
    const int part = blockIdx.x;             // 0..3: bw kc-pairs; 4: bwin
    if (part == 0 && tid == 0 && counter) *counter = 0;   // graph-replay reset
    if (part < 4) {
#pragma unroll
        for (int kk = 0; kk < 2; ++kk) {
            const int kc = part * 2 + kk;
            const float* W = (kc < 4) ? Wl : Wr;
            const int kbase = (kc & 3) * 32 + quad * 8;
            bf16x8 f0, f1;
#pragma unroll
            for (int j = 0; j < 8; ++j) {
                float2 v = *(const float2*)(W + (size_t)(kbase + j) * 128 + c0);
                f0[j] = (short)f2bf(v.x * TANH_S);
                f1[j] = (short)f2bf(v.y * TANH_S);
            }
            *(bf16x8*)(ws + (kc * 2 + 0) * 2048 + tid * 8) = f0;
            *(bf16x8*)(ws + (kc * 2 + 1) * 2048 + tid * 8) = f1;
        }
    } else {
#pragma unroll
        for (int kc = 0; kc < 2; ++kc) {
            const int kbase = kc * 32 + quad * 8;
            bf16x8 f0, f1;
#pragma unroll
            for (int j = 0; j < 8; ++j) {
                float2 v = *(const float2*)(Win + (size_t)(kbase + j) * 128 + c0);
                f0[j] = (short)f2bf(v.x * TANH_S);
                f1[j] = (short)f2bf(v.y * TANH_S);
            }
            *(bf16x8*)(ws + WS_BWIN + (kc * 2 + 0) * 2048 + tid * 8) = f0;
            *(bf16x8*)(ws + WS_BWIN + (kc * 2 + 1) * 2048 + tid * 8) = f1;
        }
    }
}

// ---- coalesced frag loads from d_ws ----------------------------------------
__device__ __forceinline__ void load_bw_ws(const u16* __restrict__ ws, int tid,
                                           bf16x8 (&bw)[8][2]) {
#pragma unroll
    for (int kc = 0; kc < 8; ++kc) {
        bw[kc][0] = *(const bf16x8*)(ws + (kc * 2 + 0) * 2048 + tid * 8);
        bw[kc][1] = *(const bf16x8*)(ws + (kc * 2 + 1) * 2048 + tid * 8);
    }
}

// ---- gather 128 bf16 rows -> swizzled H0 (uint4 = 8 bf16, zero cvt) --------
// addr(r) = base + (r>>2)*S4 + (r&3)*Sin + c8
__device__ __forceinline__ void gather128(u16* H0, const u16* base, int S4,
                                          int Sin, int tid) {
#pragma unroll
    for (int it = 0; it < 8; ++it) {
        int i4 = tid + 256 * it;
        int r = i4 >> 4, c8 = (i4 & 15) << 3;
        uint4 v = *(const uint4*)(base + (size_t)(r >> 2) * S4 + (r & 3) * Sin + c8);
        *(uint4*)(H0 + r * 136 + swz(r, c8)) = v;
    }
}

// ---- pairwise levels; at M==Mlast write bf16 rows (BFOUT) or fp32 ----------
template <bool BFOUT>
__device__ __forceinline__ void run_levels_mfma(
    u16* b0, u16* b1, int Mfirst, int Mlast, const bf16x8 (&bw)[8][2],
    float bs0, float bs1, u16* outB, int ostr, float* outF,
    int quad, int lq, int c0) {
    u16* in = b0;
    u16* out = b1;
    for (int M = Mfirst; M >= Mlast; M >>= 1) {
        const int ntiles = (M + 15) >> 4;
        for (int rt = 0; rt < ntiles; ++rt) {
            const int r0e = rt * 16;
            bf16x8 a[8];
#pragma unroll
            for (int kc = 0; kc < 8; ++kc) {
                const int row = 2 * (r0e + lq) + (kc >> 2);
                const int kb = (kc & 3) * 32 + quad * 8;
                a[kc] = *(const bf16x8*)(in + row * 136 + swz(row, kb));
            }
            f32x4 ac0 = {bs0, bs0, bs0, bs0}, ac1 = {bs1, bs1, bs1, bs1};
#pragma unroll
            for (int kc = 0; kc < 8; ++kc) {
                ac0 = MFMA16(a[kc], bw[kc][0], ac0);
                ac1 = MFMA16(a[kc], bw[kc][1], ac1);
            }
#pragma unroll
            for (int r = 0; r < 4; ++r) {
                const int ro = r0e + quad * 4 + r;
                if (ro < M) {
                    float v0 = tanh_ps(ac0[r]);
                    float v1 = tanh_ps(ac1[r]);
                    if (M == Mlast) {
                        if (BFOUT) {
                            *(u32*)(outB + ro * ostr + c0) = f2bf_pk(v0, v1);
                        } else {
                            *(float2*)(outF + ro * 128 + c0) = make_float2(v0, v1);
                        }
                    } else {
                        *(u32*)(out + ro * 136 + swz(ro, c0)) = f2bf_pk(v0, v1);
                    }
                }
            }
        }
        __syncthreads();
        u16* t = in; in = out; out = t;
    }
}

// ---- kfront: leaf GEMM + levels 1..4 for a 64-leaf subtree -----------------
// LDS 26624 B -> 6 blocks/CU (24 waves/CU). XB/l1 may alias (fallback): no
// __restrict__ on them.
__global__ __launch_bounds__(256, 4) void kfront(
    const float* XB, const float* __restrict__ bin,
    const float* __restrict__ bl, const float* __restrict__ br,
    const u16* __restrict__ ws, u16* l1, int bstr) {
    __shared__ __align__(16) u16 H0[64 * 136];    // 17408 B
    __shared__ __align__(16) u16 POOL[64 * 72];   // 9216 B: Xa, then H1[32][136]

    const int tid = threadIdx.x;
    const int w = tid >> 6, lane = tid & 63, quad = lane >> 4, lq = lane & 15;
    const int b = blockIdx.x;
    const int c0 = 32 * w + 2 * lq;               // pair (c0, c0+1)
    u16* Xa = POOL;   // [64][72] bf16 leaf inputs
    u16* H1 = POOL;   // [32][136] after leaf phase (Xa dead)

    const float* Xg = XB + (size_t)b * 4096;      // 64 rows x 64
#pragma unroll
    for (int t = 0; t < 4; ++t) {
        int i4 = tid + 256 * t;
        int r = i4 >> 4, k4 = (i4 & 15) << 2;
        float4 v = *(const float4*)(Xg + r * 64 + k4);
        *(uint2*)(Xa + r * 72 + k4) =
            make_uint2(f2bf_pk(v.x, v.y), f2bf_pk(v.z, v.w));
    }

    bf16x8 bwin[2][2];
#pragma unroll
    for (int kc = 0; kc < 2; ++kc) {
        bwin[kc][0] = *(const bf16x8*)(ws + WS_BWIN + (kc * 2 + 0) * 2048 + tid * 8);
        bwin[kc][1] = *(const bf16x8*)(ws + WS_BWIN + (kc * 2 + 1) * 2048 + tid * 8);
    }
    bf16x8 bw[8][2];
    load_bw_ws(ws, tid, bw);

    const float2 binp = *(const float2*)(bin + c0);
    const float2 blp = *(const float2*)(bl + c0);
    const float2 brp = *(const float2*)(br + c0);
    const float bi0 = binp.x * TANH_S, bi1 = binp.y * TANH_S;
    const float bs0 = (blp.x + brp.x) * TANH_S, bs1 = (blp.y + brp.y) * TANH_S;
    __syncthreads();

    // leaf GEMM: [64x64] @ [64x128], 4 row-tiles, K=64 = 2 MFMA per acc
    for (int rt = 0; rt < 4; ++rt) {
        const int r0e = rt * 16;
        const int rowa = r0e + lq;
        bf16x8 a0 = *(const bf16x8*)(Xa + rowa * 72 + quad * 8);
        bf16x8 a1 = *(const bf16x8*)(Xa + rowa * 72 + 32 + quad * 8);
        f32x4 ac0 = {bi0, bi0, bi0, bi0}, ac1 = {bi1, bi1, bi1, bi1};
        ac0 = MFMA16(a0, bwin[0][0], ac0);
        ac0 = MFMA16(a1, bwin[1][0], ac0);
        ac1 = MFMA16(a0, bwin[0][1], ac1);
        ac1 = MFMA16(a1, bwin[1][1], ac1);
#pragma unroll
        for (int r = 0; r < 4; ++r) {
            const int ro = r0e + quad * 4 + r;
            *(u32*)(H0 + ro * 136 + swz(ro, c0)) =
                f2bf_pk(tanh_ps(ac0[r]), tanh_ps(ac1[r]));
        }
    }
    __syncthreads();   // H0 complete; Xa reads done (H1 aliases Xa)

    // levels 1..4 (M=32..4); write 4 bf16 rows (row stride 128) to l1
    run_levels_mfma<true>(H0, H1, 32, 4, bw, bs0, bs1,
                          l1 + (size_t)b * bstr, 128, nullptr, quad, lq, c0);
}

// ---- kmid: 128 blocks, levels 5..11 -> 1 row; last block runs tail ---------
__global__ __launch_bounds__(256) void kmid(
    const u16* l1, int bstr, const float* __restrict__ bl,
    const float* __restrict__ br, const u16* __restrict__ ws,
    u16* l2, int lstr, float* __restrict__ out, u32* counter, int do_tail) {
    __shared__ __align__(16) u16 H0[128 * 136];   // 34816 B
    __shared__ __align__(16) u16 H1[64 * 136];    // 17408 B
    __shared__ int amlast;

    const int tid = threadIdx.x;
    const int w = tid >> 6, lane = tid & 63, quad = lane >> 4, lq = lane & 15;
    const int t = blockIdx.x;
    const int c0 = 32 * w + 2 * lq;

    bf16x8 bw[8][2];
    load_bw_ws(ws, tid, bw);

    // 128 bf16 rows from kfront blocks 32t..32t+31 (4 rows each)
    gather128(H0, l1 + (size_t)(32 * t) * bstr, bstr, 128, tid);

    const float2 blp = *(const float2*)(bl + c0);
    const float2 brp = *(const float2*)(br + c0);
    const float bs0 = (blp.x + brp.x) * TANH_S, bs1 = (blp.y + brp.y) * TANH_S;
    __syncthreads();

    run_levels_mfma<true>(H0, H1, 64, 1, bw, bs0, bs1,
                          l2 + (size_t)t * lstr, 128, nullptr, quad, lq, c0);

    if (!do_tail) return;
    // ---- merged tail: last block to finish runs levels 12..18 --------------
    __threadfence();                       // agent-scope release (cross-XCD)
    __syncthreads();
    if (tid == 0) amlast = (atomicAdd(counter, 1u) == 127u) ? 1 : 0;
    __syncthreads();
    if (!amlast) return;
    __threadfence();                       // acquire side

    gather128(H0, l2, 4 * lstr, lstr, tid);
    __syncthreads();
    run_levels_mfma<false>(H0, H1, 64, 1, bw, bs0, bs1,
                           nullptr, 0, out, quad, lq, c0);
}

// ---- ktail: fallback-only (small ws) ---------------------------------------
__global__ __launch_bounds__(256) void ktail(
    const u16* l2, int lstr, const float* __restrict__ bl,
    const float* __restrict__ br, const u16* __restrict__ ws,
    float* __restrict__ out) {
    __shared__ __align__(16) u16 H0[128 * 136];
    __shared__ __align__(16) u16 H1[64 * 136];

    const int tid = threadIdx.x;
    const int w = tid >> 6, lane = tid & 63, quad = lane >> 4, lq = lane & 15;
    const int c0 = 32 * w + 2 * lq;

    bf16x8 bw[8][2];
    load_bw_ws(ws, tid, bw);
    gather128(H0, l2, 4 * lstr, lstr, tid);

    const float2 blp = *(const float2*)(bl + c0);
    const float2 brp = *(const float2*)(br + c0);
    const float bs0 = (blp.x + brp.x) * TANH_S, bs1 = (blp.y + brp.y) * TANH_S;
    __syncthreads();

    run_levels_mfma<false>(H0, H1, 64, 1, bw, bs0, bs1,
                           nullptr, 0, out, quad, lq, c0);
}

// ---- host ------------------------------------------------------------------
extern "C" void kernel_launch(void* const* d_in, const int* in_sizes, int n_in,
                              void* d_out, int out_size, void* d_ws, size_t ws_size,
                              hipStream_t stream) {
    float* XB = (float*)d_in[0];
    const float* Win = (const float*)d_in[1];
    const float* bin = (const float*)d_in[2];
    const float* Wl  = (const float*)d_in[3];
    const float* bl  = (const float*)d_in[4];
    const float* Wr  = (const float*)d_in[5];
    const float* br  = (const float*)d_in[6];
    float* out = (float*)d_out;
    u16* ws = (u16*)d_ws;                     // frags always here (>=81920 B)

    const bool big = (d_ws != nullptr) && (ws_size >= (size_t)WS_NEED);
    u16* l1; int bstr; u16* l2; int lstr; u32* counter; int do_tail;
    if (big) {
        // XB is never written: all scratch lives in d_ws.
        l1 = (u16*)((char*)d_ws + WS_L1_BYTE); bstr = 512;   // contiguous rows
        l2 = (u16*)((char*)d_ws + WS_L2_BYTE); lstr = 128;
        counter = (u32*)((char*)d_ws + WS_CNT_BYTE);
        do_tail = 1;
    } else {
        // fallback: per-block dead zones of consumed XB regions
        l1 = (u16*)XB;        bstr = 8192;    // block region = 4096 floats
        l2 = (u16*)XB + 4096; lstr = 8192;    // region float 2048 (dead zone)
        counter = nullptr;
        do_tail = 0;
    }

    kprep<<<5, 256, 0, stream>>>(Win, Wl, Wr, ws, counter);
    kfront<<<4096, 256, 0, stream>>>(XB, bin, bl, br, ws, l1, bstr);
    kmid<<<128, 256, 0, stream>>>(l1, bstr, bl, br, ws, l2, lstr, out, counter, do_tail);
    if (!do_tail)
        ktail<<<1, 256, 0, stream>>>(l2, lstr, bl, br, ws, out);
}

// Round 3
// 132.142 us; speedup vs baseline: 1.1596x; 1.1596x over previous
//
#include <hip/hip_runtime.h>
#include <hip/hip_bf16.h>

// RecursiveNN, perfect binary tree. N=262144 leaves, IN=64, HID=128.
// SETTLED: inputs fp32 jax-layout ([K,N] weights), output fp32[128].
// R10: 168.4us. R11: 142.0us (prestaged frags in 80KB ws, tanh-scale fold,
//   bias-in-acc). R12 REGRESSION 153.2us: 64-leaf kfront (more fixed cost,
//   occupancy wasn't the limiter) + ws>4.3MB path likely fell back untested.
// R13 (this): revert to R11-proven structure/memory scheme; ONE new lever:
//   compile-time level unrolling. run_levels' M is now a template parameter
//   (recursive chain), so tile loops fully unroll, LDS in/out buffers become
//   fixed __shared__ bases, and the swizzle XOR ((row>>3)&3) -- invariant
//   across tiles since row steps by 32 -- folds into per-thread constant
//   addresses + ds offset immediates. Targets the 57%-VALUBusy issue floor.
//   Intermediates stay bf16 (proven R12): l1 = 4 bf16 rows at each kfront
//   region start; l2 = 1 bf16 row per kmid block at region+8192 u16.
//
//  kprep  5 blocks: W frags (scaled by 2/ln2) -> d_ws (80KB, proven size).
//  kfront b (2048): leaf GEMM + levels 1..5 on 128 leaves -> 4 bf16 rows at
//            XBu16[b*16384] (own consumed region).
//  kmid t (64): gather 128 bf16 rows from kfront blocks 32t..32t+31,
//            levels 6..12 -> 1 bf16 row at XBu16[32t*16384 + 8192].
//  ktail: 64 rows -> levels 13..18 -> root fp32[128] -> d_out.
// H LDS: row stride 136 bf16, col swizzle c ^ (((row>>3)&3)<<3).

typedef unsigned short u16;
typedef unsigned int u32;
typedef __attribute__((ext_vector_type(8))) short bf16x8;   // 8 bf16, 4 VGPR
typedef __attribute__((ext_vector_type(4))) float f32x4;

#define TANH_S 2.8853900817779268f  // 2/ln2; tanh(x) = 1 - 2/(exp2(S*x)+1)

__device__ __forceinline__ u16 f2bf(float f) {
    __hip_bfloat16 h = __float2bfloat16(f);   // RNE
    return *(u16*)&h;
}
__device__ __forceinline__ u32 f2bf_pk(float a, float b) {
    __hip_bfloat162 h = __float22bfloat162_rn(make_float2(a, b));
    return *(u32*)&h;
}
// NaN-free tanh, input PRE-SCALED by TANH_S (scale folded into weights/bias)
__device__ __forceinline__ float tanh_ps(float xs) {
#if __has_builtin(__builtin_amdgcn_exp2f) && __has_builtin(__builtin_amdgcn_rcpf)
    float t = __builtin_amdgcn_exp2f(xs);
    float r = __builtin_amdgcn_rcpf(t + 1.0f);
    return __builtin_fmaf(-2.0f, r, 1.0f);
#else
    float e = __expf(xs * 0.6931471805599453f);
    return 1.0f - 2.0f / (e + 1.0f);
#endif
}
__device__ __forceinline__ int swz(int row, int c) {
    return c ^ (((row >> 3) & 3) << 3);
}

#define MFMA16(a, b, c) __builtin_amdgcn_mfma_f32_16x16x32_bf16((a), (b), (c), 0, 0, 0)

// ---- d_ws frag layout (u16 units) -- identical to proven R11 ---------------
// bw   slot s = kc*2+i (16 slots): ws[s*2048 + tid*8]  -> 65536 B
// bwin slot s = kc*2+i ( 4 slots): ws[32768 + s*2048 + tid*8] -> 16384 B
#define WS_BWIN 32768
#define WS_BYTES 81920

// ---- kprep: materialize bf16 B-frags (scaled by TANH_S) into d_ws ----------
__global__ __launch_bounds__(256) void kprep(
    const float* __restrict__ Win, const float* __restrict__ Wl,
    const float* __restrict__ Wr, u16* __restrict__ ws) {
    const int tid = threadIdx.x;
    const int w = tid >> 6, lane = tid & 63, quad = lane >> 4, lq = lane & 15;
    const int c0 = 32 * w + 2 * lq;
    const int part = blockIdx.x;             // 0..3: bw kc-pairs; 4: bwin
    if (part < 4) {
#pragma unroll
        for (int kk = 0; kk < 2; ++kk) {
            const int kc = part * 2 + kk;
            const float* W = (kc < 4) ? Wl : Wr;
            const int kbase = (kc & 3) * 32 + quad * 8;
            bf16x8 f0, f1;
#pragma unroll
            for (int j = 0; j < 8; ++j) {
                float2 v = *(const float2*)(W + (size_t)(kbase + j) * 128 + c0);
                f0[j] = (short)f2bf(v.x * TANH_S);
                f1[j] = (short)f2bf(v.y * TANH_S);
            }
            *(bf16x8*)(ws + (kc * 2 + 0) * 2048 + tid * 8) = f0;
            *(bf16x8*)(ws + (kc * 2 + 1) * 2048 + tid * 8) = f1;
        }
    } else {
#pragma unroll
        for (int kc = 0; kc < 2; ++kc) {
            const int kbase = kc * 32 + quad * 8;
            bf16x8 f0, f1;
#pragma unroll
            for (int j = 0; j < 8; ++j) {
                float2 v = *(const float2*)(Win + (size_t)(kbase + j) * 128 + c0);
                f0[j] = (short)f2bf(v.x * TANH_S);
                f1[j] = (short)f2bf(v.y * TANH_S);
            }
            *(bf16x8*)(ws + WS_BWIN + (kc * 2 + 0) * 2048 + tid * 8) = f0;
            *(bf16x8*)(ws + WS_BWIN + (kc * 2 + 1) * 2048 + tid * 8) = f1;
        }
    }
}

// ---- coalesced frag loads from d_ws ----------------------------------------
__device__ __forceinline__ void load_bw_ws(const u16* __restrict__ ws, int tid,
                                           bf16x8 (&bw)[8][2]) {
#pragma unroll
    for (int kc = 0; kc < 8; ++kc) {
        bw[kc][0] = *(const bf16x8*)(ws + (kc * 2 + 0) * 2048 + tid * 8);
        bw[kc][1] = *(const bf16x8*)(ws + (kc * 2 + 1) * 2048 + tid * 8);
    }
}

// ---- gather 128 bf16 rows -> swizzled H0 (uint4 = 8 bf16, zero cvt) --------
// addr(r) = base + (r>>2)*S4 + (r&3)*Sin + c8
__device__ __forceinline__ void gather128(u16* H0, const u16* base, int S4,
                                          int Sin, int tid) {
#pragma unroll
    for (int it = 0; it < 8; ++it) {
        int i4 = tid + 256 * it;
        int r = i4 >> 4, c8 = (i4 & 15) << 3;
        uint4 v = *(const uint4*)(base + (size_t)(r >> 2) * S4 + (r & 3) * Sin + c8);
        *(uint4*)(H0 + r * 136 + swz(r, c8)) = v;
    }
}

// ---- compile-time level chain: M outputs from 2M rows of `in` --------------
// At M==Mlast: write bf16 rows (BFOUT) or fp32 rows to global.
// All M/r0e constant -> tile loops unroll, LDS addrs fold to const+imm.
template <int M, int Mlast, bool BFOUT>
__device__ __forceinline__ void level_chain(
    u16* in, u16* nxt, const bf16x8 (&bw)[8][2], float bs0, float bs1,
    u16* outB, int ostrB, float* outF, int quad, int lq, int c0) {
    constexpr int ntiles = (M + 15) >> 4;
#pragma unroll
    for (int rt = 0; rt < ntiles; ++rt) {
        const int r0e = rt * 16;
        bf16x8 a[8];
#pragma unroll
        for (int kc = 0; kc < 8; ++kc) {
            const int row = 2 * (r0e + lq) + (kc >> 2);
            const int kb = (kc & 3) * 32 + quad * 8;
            a[kc] = *(const bf16x8*)(in + row * 136 + swz(row, kb));
        }
        f32x4 ac0 = {bs0, bs0, bs0, bs0}, ac1 = {bs1, bs1, bs1, bs1};
#pragma unroll
        for (int kc = 0; kc < 8; ++kc) {
            ac0 = MFMA16(a[kc], bw[kc][0], ac0);
            ac1 = MFMA16(a[kc], bw[kc][1], ac1);
        }
#pragma unroll
        for (int r = 0; r < 4; ++r) {
            const int ro = r0e + quad * 4 + r;
            if (ro < M) {
                float v0 = tanh_ps(ac0[r]);
                float v1 = tanh_ps(ac1[r]);
                if constexpr (M == Mlast) {
                    if constexpr (BFOUT) {
                        *(u32*)(outB + ro * ostrB + c0) = f2bf_pk(v0, v1);
                    } else {
                        *(float2*)(outF + ro * 128 + c0) = make_float2(v0, v1);
                    }
                } else {
                    *(u32*)(nxt + ro * 136 + swz(ro, c0)) = f2bf_pk(v0, v1);
                }
            }
        }
    }
    __syncthreads();
    if constexpr (M > Mlast)
        level_chain<(M >> 1), Mlast, BFOUT>(nxt, in, bw, bs0, bs1,
                                            outB, ostrB, outF, quad, lq, c0);
}

// ---- kfront: leaf GEMM + levels 1..5 for a 128-leaf subtree ----------------
__global__ __launch_bounds__(256, 2) void kfront(
    float* XB, const float* __restrict__ bin,
    const float* __restrict__ bl, const float* __restrict__ br,
    const u16* __restrict__ ws) {
    __shared__ __align__(16) u16 H0[128 * 136];   // 34816 B
    __shared__ __align__(16) u16 POOL[128 * 72];  // 18432 B: Xa, then H1
    // 53248 B total

    const int tid = threadIdx.x;
    const int w = tid >> 6, lane = tid & 63, quad = lane >> 4, lq = lane & 15;
    const int b = blockIdx.x;
    const int c0 = 32 * w + 2 * lq;               // pair (c0, c0+1)
    u16* Xa = POOL;   // [128][72] bf16 leaf inputs
    u16* H1 = POOL;   // [64][136] after leaf phase (Xa dead)

    const float* Xg = XB + (size_t)b * 8192;      // 128 rows x 64
#pragma unroll
    for (int t = 0; t < 8; ++t) {
        int i4 = tid + 256 * t;
        int r = i4 >> 4, k4 = (i4 & 15) << 2;
        float4 v = *(const float4*)(Xg + r * 64 + k4);
        *(uint2*)(Xa + r * 72 + k4) =
            make_uint2(f2bf_pk(v.x, v.y), f2bf_pk(v.z, v.w));
    }

    bf16x8 bwin[2][2];
#pragma unroll
    for (int kc = 0; kc < 2; ++kc) {
        bwin[kc][0] = *(const bf16x8*)(ws + WS_BWIN + (kc * 2 + 0) * 2048 + tid * 8);
        bwin[kc][1] = *(const bf16x8*)(ws + WS_BWIN + (kc * 2 + 1) * 2048 + tid * 8);
    }
    bf16x8 bw[8][2];
    load_bw_ws(ws, tid, bw);

    const float2 binp = *(const float2*)(bin + c0);
    const float2 blp = *(const float2*)(bl + c0);
    const float2 brp = *(const float2*)(br + c0);
    const float bi0 = binp.x * TANH_S, bi1 = binp.y * TANH_S;
    const float bs0 = (blp.x + brp.x) * TANH_S, bs1 = (blp.y + brp.y) * TANH_S;
    __syncthreads();

    // leaf GEMM: [128x64] @ [64x128], 8 row-tiles, K=64 = 2 MFMA per acc
#pragma unroll
    for (int rt = 0; rt < 8; ++rt) {
        const int r0e = rt * 16;
        const int rowa = r0e + lq;
        bf16x8 a0 = *(const bf16x8*)(Xa + rowa * 72 + quad * 8);
        bf16x8 a1 = *(const bf16x8*)(Xa + rowa * 72 + 32 + quad * 8);
        f32x4 ac0 = {bi0, bi0, bi0, bi0}, ac1 = {bi1, bi1, bi1, bi1};
        ac0 = MFMA16(a0, bwin[0][0], ac0);
        ac0 = MFMA16(a1, bwin[1][0], ac0);
        ac1 = MFMA16(a0, bwin[0][1], ac1);
        ac1 = MFMA16(a1, bwin[1][1], ac1);
#pragma unroll
        for (int r = 0; r < 4; ++r) {
            const int ro = r0e + quad * 4 + r;
            *(u32*)(H0 + ro * 136 + swz(ro, c0)) =
                f2bf_pk(tanh_ps(ac0[r]), tanh_ps(ac1[r]));
        }
    }
    __syncthreads();   // H0 complete; Xa reads done (H1 aliases Xa)

    // levels 1..5 (M=64..4); write 4 bf16 rows (stride 128 u16) into own
    // consumed region: XBu16[b*16384]
    u16* l1 = (u16*)XB + (size_t)b * 16384;
    level_chain<64, 4, true>(H0, H1, bw, bs0, bs1, l1, 128, nullptr,
                             quad, lq, c0);
}

// ---- kmid: 64 blocks, gather 128 rows, levels 6..12 -> 1 bf16 row ----------
__global__ __launch_bounds__(256) void kmid(
    float* XB, const float* __restrict__ bl, const float* __restrict__ br,
    const u16* __restrict__ ws) {
    __shared__ __align__(16) u16 H0[128 * 136];   // 34816 B
    __shared__ __align__(16) u16 H1[64 * 136];    // 17408 B

    const int tid = threadIdx.x;
    const int w = tid >> 6, lane = tid & 63, quad = lane >> 4, lq = lane & 15;
    const int t = blockIdx.x;
    const int c0 = 32 * w + 2 * lq;

    bf16x8 bw[8][2];
    load_bw_ws(ws, tid, bw);

    // 128 bf16 rows from kfront blocks 32t..32t+31 (4 rows each, stride 128)
    const u16* l1 = (const u16*)XB + (size_t)(32 * t) * 16384;
    gather128(H0, l1, 16384, 128, tid);

    const float2 blp = *(const float2*)(bl + c0);
    const float2 brp = *(const float2*)(br + c0);
    const float bs0 = (blp.x + brp.x) * TANH_S, bs1 = (blp.y + brp.y) * TANH_S;
    __syncthreads();

    // 7 levels {64..1}; 1 bf16 row -> dead zone of region 32t (u16 ofs 8192)
    u16* l2 = (u16*)XB + (size_t)(32 * t) * 16384 + 8192;
    level_chain<64, 1, true>(H0, H1, bw, bs0, bs1, l2, 128, nullptr,
                             quad, lq, c0);
}

// ---- ktail: 64 rows -> levels 13..18 -> root fp32 --------------------------
__global__ __launch_bounds__(256) void ktail(
    const float* XB, const float* __restrict__ bl, const float* __restrict__ br,
    const u16* __restrict__ ws, float* __restrict__ out) {
    __shared__ __align__(16) u16 H0[64 * 136];
    __shared__ __align__(16) u16 H1[64 * 136];

    const int tid = threadIdx.x;
    const int w = tid >> 6, lane = tid & 63, quad = lane >> 4, lq = lane & 15;
    const int c0 = 32 * w + 2 * lq;

    bf16x8 bw[8][2];
    load_bw_ws(ws, tid, bw);

    // 64 bf16 rows: row r at XBu16[32r*16384 + 8192]
    const u16* base = (const u16*)XB + 8192;
#pragma unroll
    for (int it = 0; it < 4; ++it) {
        int i4 = threadIdx.x + 256 * it;
        int r = i4 >> 4, c8 = (i4 & 15) << 3;     // r = 0..63
        uint4 v = *(const uint4*)(base + (size_t)r * (32 * 16384) + c8);
        *(uint4*)(H0 + r * 136 + swz(r, c8)) = v;
    }
    const float2 blp = *(const float2*)(bl + c0);
    const float2 brp = *(const float2*)(br + c0);
    const float bs0 = (blp.x + brp.x) * TANH_S, bs1 = (blp.y + brp.y) * TANH_S;
    __syncthreads();

    // 6 levels {32..1} -> root fp32[128]
    level_chain<32, 1, false>(H0, H1, bw, bs0, bs1, nullptr, 0, out,
                              quad, lq, c0);
}

// ---- host ------------------------------------------------------------------
extern "C" void kernel_launch(void* const* d_in, const int* in_sizes, int n_in,
                              void* d_out, int out_size, void* d_ws, size_t ws_size,
                              hipStream_t stream) {
    float* XB = (float*)d_in[0];              // consumed then reused in-place
    const float* Win = (const float*)d_in[1];
    const float* bin = (const float*)d_in[2];
    const float* Wl  = (const float*)d_in[3];
    const float* bl  = (const float*)d_in[4];
    const float* Wr  = (const float*)d_in[5];
    const float* br  = (const float*)d_in[6];
    float* out = (float*)d_out;
    u16* ws = (u16*)d_ws;                     // 81920 B (proven in R11)

    kprep<<<5, 256, 0, stream>>>(Win, Wl, Wr, ws);
    kfront<<<2048, 256, 0, stream>>>(XB, bin, bl, br, ws);
    kmid<<<64, 256, 0, stream>>>(XB, bl, br, ws);
    ktail<<<1, 256, 0, stream>>>(XB, bl, br, ws, out);
}

// Round 4
// 131.270 us; speedup vs baseline: 1.1673x; 1.0066x over previous
//
#include <hip/hip_runtime.h>
#include <hip/hip_bf16.h>

// RecursiveNN, perfect binary tree. N=262144 leaves, IN=64, HID=128.
// SETTLED: inputs fp32 jax-layout ([K,N] weights), output fp32[128].
// R11: 142.0us (prestaged frags in 80KB ws, tanh fold, bias-in-acc).
// R12 REGRESSION 153.2: bundled 4 changes. R13: 132.1us (compile-time level
//   unroll; kfront ~31us, below the 41us ws-poison fills in the trace).
// R14 (this): XB becomes READ-ONLY -- l1/l2 intermediates live in d_ws
//   (ws is >=256MiB per the fill size in rocprof). Removes any input-restore
//   from the timed path; makes l1/l2 fully contiguous (coalesced gathers).
//   kfront now stops at M=8 (drops the 75%-masked M=4 tile + 1 barrier);
//   kmid = 128 blocks (16 regions x 8 rows), ktail starts at 128 rows.
//   Fallback to R13's XB dead-zone scheme if ws_size < ~4.4MB.
//
//  kprep  5 blocks: W frags (scaled by 2/ln2) -> ws[0..80KB).
//  kfront b (2048): leaf GEMM + levels 1..4 on 128 leaves -> 8 bf16 rows at
//            l1 + b*1024 (ws-mode: contiguous).
//  kmid t (128): gather 128 bf16 rows from kfront blocks 16t..16t+15,
//            levels 5..11 -> 1 bf16 row at l2 + t*128.
//  ktail: 128 rows -> levels 12..18 -> root fp32[128] -> d_out.
// H LDS: row stride 136 bf16, col swizzle c ^ (((row>>3)&3)<<3).

typedef unsigned short u16;
typedef unsigned int u32;
typedef __attribute__((ext_vector_type(8))) short bf16x8;   // 8 bf16, 4 VGPR
typedef __attribute__((ext_vector_type(4))) float f32x4;

#define TANH_S 2.8853900817779268f  // 2/ln2; tanh(x) = 1 - 2/(exp2(S*x)+1)

__device__ __forceinline__ u16 f2bf(float f) {
    __hip_bfloat16 h = __float2bfloat16(f);   // RNE
    return *(u16*)&h;
}
__device__ __forceinline__ u32 f2bf_pk(float a, float b) {
    __hip_bfloat162 h = __float22bfloat162_rn(make_float2(a, b));
    return *(u32*)&h;
}
// NaN-free tanh, input PRE-SCALED by TANH_S (scale folded into weights/bias)
__device__ __forceinline__ float tanh_ps(float xs) {
#if __has_builtin(__builtin_amdgcn_exp2f) && __has_builtin(__builtin_amdgcn_rcpf)
    float t = __builtin_amdgcn_exp2f(xs);
    float r = __builtin_amdgcn_rcpf(t + 1.0f);
    return __builtin_fmaf(-2.0f, r, 1.0f);
#else
    float e = __expf(xs * 0.6931471805599453f);
    return 1.0f - 2.0f / (e + 1.0f);
#endif
}
__device__ __forceinline__ int swz(int row, int c) {
    return c ^ (((row >> 3) & 3) << 3);
}

#define MFMA16(a, b, c) __builtin_amdgcn_mfma_f32_16x16x32_bf16((a), (b), (c), 0, 0, 0)

// ---- d_ws layout ------------------------------------------------------------
// frags (u16): bw slot s=kc*2+i (16 slots) at ws[s*2048 + tid*8];
//              bwin (4 slots) at ws[32768 + s*2048 + tid*8].  81920 B.
// ws-mode scratch: L1 bf16 [2048*8][128] at byte 81920 (4194304 B)
//                  L2 bf16 [128][128]    at byte 4276224 (32768 B)
#define WS_BWIN 32768
#define WS_L1_BYTE 81920
#define WS_L2_BYTE (WS_L1_BYTE + 4194304)
#define WS_NEED (WS_L2_BYTE + 32768)

// ---- kprep: materialize bf16 B-frags (scaled by TANH_S) into d_ws ----------
__global__ __launch_bounds__(256) void kprep(
    const float* __restrict__ Win, const float* __restrict__ Wl,
    const float* __restrict__ Wr, u16* __restrict__ ws) {
    const int tid = threadIdx.x;
    const int w = tid >> 6, lane = tid & 63, quad = lane >> 4, lq = lane & 15;
    const int c0 = 32 * w + 2 * lq;
    const int part = blockIdx.x;             // 0..3: bw kc-pairs; 4: bwin
    if (part < 4) {
#pragma unroll
        for (int kk = 0; kk < 2; ++kk) {
            const int kc = part * 2 + kk;
            const float* W = (kc < 4) ? Wl : Wr;
            const int kbase = (kc & 3) * 32 + quad * 8;
            bf16x8 f0, f1;
#pragma unroll
            for (int j = 0; j < 8; ++j) {
                float2 v = *(const float2*)(W + (size_t)(kbase + j) * 128 + c0);
                f0[j] = (short)f2bf(v.x * TANH_S);
                f1[j] = (short)f2bf(v.y * TANH_S);
            }
            *(bf16x8*)(ws + (kc * 2 + 0) * 2048 + tid * 8) = f0;
            *(bf16x8*)(ws + (kc * 2 + 1) * 2048 + tid * 8) = f1;
        }
    } else {
#pragma unroll
        for (int kc = 0; kc < 2; ++kc) {
            const int kbase = kc * 32 + quad * 8;
            bf16x8 f0, f1;
#pragma unroll
            for (int j = 0; j < 8; ++j) {
                float2 v = *(const float2*)(Win + (size_t)(kbase + j) * 128 + c0);
                f0[j] = (short)f2bf(v.x * TANH_S);
                f1[j] = (short)f2bf(v.y * TANH_S);
            }
            *(bf16x8*)(ws + WS_BWIN + (kc * 2 + 0) * 2048 + tid * 8) = f0;
            *(bf16x8*)(ws + WS_BWIN + (kc * 2 + 1) * 2048 + tid * 8) = f1;
        }
    }
}

// ---- coalesced frag loads from d_ws ----------------------------------------
__device__ __forceinline__ void load_bw_ws(const u16* __restrict__ ws, int tid,
                                           bf16x8 (&bw)[8][2]) {
#pragma unroll
    for (int kc = 0; kc < 8; ++kc) {
        bw[kc][0] = *(const bf16x8*)(ws + (kc * 2 + 0) * 2048 + tid * 8);
        bw[kc][1] = *(const bf16x8*)(ws + (kc * 2 + 1) * 2048 + tid * 8);
    }
}

// ---- compile-time level chain: M outputs from 2M rows of `in` --------------
// At M==Mlast: write bf16 rows (BFOUT, row stride 128 u16) or fp32 rows.
template <int M, int Mlast, bool BFOUT>
__device__ __forceinline__ void level_chain(
    u16* in, u16* nxt, const bf16x8 (&bw)[8][2], float bs0, float bs1,
    u16* outB, float* outF, int quad, int lq, int c0) {
    constexpr int ntiles = (M + 15) >> 4;
#pragma unroll
    for (int rt = 0; rt < ntiles; ++rt) {
        const int r0e = rt * 16;
        bf16x8 a[8];
#pragma unroll
        for (int kc = 0; kc < 8; ++kc) {
            const int row = 2 * (r0e + lq) + (kc >> 2);
            const int kb = (kc & 3) * 32 + quad * 8;
            a[kc] = *(const bf16x8*)(in + row * 136 + swz(row, kb));
        }
        f32x4 ac0 = {bs0, bs0, bs0, bs0}, ac1 = {bs1, bs1, bs1, bs1};
#pragma unroll
        for (int kc = 0; kc < 8; ++kc) {
            ac0 = MFMA16(a[kc], bw[kc][0], ac0);
            ac1 = MFMA16(a[kc], bw[kc][1], ac1);
        }
#pragma unroll
        for (int r = 0; r < 4; ++r) {
            const int ro = r0e + quad * 4 + r;
            if (ro < M) {
                float v0 = tanh_ps(ac0[r]);
                float v1 = tanh_ps(ac1[r]);
                if constexpr (M == Mlast) {
                    if constexpr (BFOUT) {
                        *(u32*)(outB + ro * 128 + c0) = f2bf_pk(v0, v1);
                    } else {
                        *(float2*)(outF + ro * 128 + c0) = make_float2(v0, v1);
                    }
                } else {
                    *(u32*)(nxt + ro * 136 + swz(ro, c0)) = f2bf_pk(v0, v1);
                }
            }
        }
    }
    __syncthreads();
    if constexpr (M > Mlast)
        level_chain<(M >> 1), Mlast, BFOUT>(nxt, in, bw, bs0, bs1,
                                            outB, outF, quad, lq, c0);
}

// ---- kfront: leaf GEMM + levels 1..4 for a 128-leaf subtree ----------------
__global__ __launch_bounds__(256, 2) void kfront(
    const float* XB, const float* __restrict__ bin,
    const float* __restrict__ bl, const float* __restrict__ br,
    const u16* __restrict__ ws, u16* l1, int l1s) {
    __shared__ __align__(16) u16 H0[128 * 136];   // 34816 B
    __shared__ __align__(16) u16 POOL[128 * 72];  // 18432 B: Xa, then H1
    // 53248 B total

    const int tid = threadIdx.x;
    const int w = tid >> 6, lane = tid & 63, quad = lane >> 4, lq = lane & 15;
    const int b = blockIdx.x;
    const int c0 = 32 * w + 2 * lq;               // pair (c0, c0+1)
    u16* Xa = POOL;   // [128][72] bf16 leaf inputs
    u16* H1 = POOL;   // [64][136] after leaf phase (Xa dead)

    const float* Xg = XB + (size_t)b * 8192;      // 128 rows x 64
#pragma unroll
    for (int t = 0; t < 8; ++t) {
        int i4 = tid + 256 * t;
        int r = i4 >> 4, k4 = (i4 & 15) << 2;
        float4 v = *(const float4*)(Xg + r * 64 + k4);
        *(uint2*)(Xa + r * 72 + k4) =
            make_uint2(f2bf_pk(v.x, v.y), f2bf_pk(v.z, v.w));
    }

    bf16x8 bwin[2][2];
#pragma unroll
    for (int kc = 0; kc < 2; ++kc) {
        bwin[kc][0] = *(const bf16x8*)(ws + WS_BWIN + (kc * 2 + 0) * 2048 + tid * 8);
        bwin[kc][1] = *(const bf16x8*)(ws + WS_BWIN + (kc * 2 + 1) * 2048 + tid * 8);
    }
    bf16x8 bw[8][2];
    load_bw_ws(ws, tid, bw);

    const float2 binp = *(const float2*)(bin + c0);
    const float2 blp = *(const float2*)(bl + c0);
    const float2 brp = *(const float2*)(br + c0);
    const float bi0 = binp.x * TANH_S, bi1 = binp.y * TANH_S;
    const float bs0 = (blp.x + brp.x) * TANH_S, bs1 = (blp.y + brp.y) * TANH_S;
    __syncthreads();

    // leaf GEMM: [128x64] @ [64x128], 8 row-tiles, K=64 = 2 MFMA per acc
#pragma unroll
    for (int rt = 0; rt < 8; ++rt) {
        const int r0e = rt * 16;
        const int rowa = r0e + lq;
        bf16x8 a0 = *(const bf16x8*)(Xa + rowa * 72 + quad * 8);
        bf16x8 a1 = *(const bf16x8*)(Xa + rowa * 72 + 32 + quad * 8);
        f32x4 ac0 = {bi0, bi0, bi0, bi0}, ac1 = {bi1, bi1, bi1, bi1};
        ac0 = MFMA16(a0, bwin[0][0], ac0);
        ac0 = MFMA16(a1, bwin[1][0], ac0);
        ac1 = MFMA16(a0, bwin[0][1], ac1);
        ac1 = MFMA16(a1, bwin[1][1], ac1);
#pragma unroll
        for (int r = 0; r < 4; ++r) {
            const int ro = r0e + quad * 4 + r;
            *(u32*)(H0 + ro * 136 + swz(ro, c0)) =
                f2bf_pk(tanh_ps(ac0[r]), tanh_ps(ac1[r]));
        }
    }
    __syncthreads();   // H0 complete; Xa reads done (H1 aliases Xa)

    // levels 1..4 (M=64..8); write 8 bf16 rows (stride 128 u16) to l1
    level_chain<64, 8, true>(H0, H1, bw, bs0, bs1,
                             l1 + (size_t)b * l1s, nullptr, quad, lq, c0);
}

// ---- kmid: 128 blocks, gather 16 regions x 8 rows, levels 5..11 -> 1 row ---
__global__ __launch_bounds__(256) void kmid(
    const u16* l1, int l1s, const float* __restrict__ bl,
    const float* __restrict__ br, const u16* __restrict__ ws,
    u16* l2, size_t l2s) {
    __shared__ __align__(16) u16 H0[128 * 136];   // 34816 B
    __shared__ __align__(16) u16 H1[64 * 136];    // 17408 B

    const int tid = threadIdx.x;
    const int w = tid >> 6, lane = tid & 63, quad = lane >> 4, lq = lane & 15;
    const int t = blockIdx.x;
    const int c0 = 32 * w + 2 * lq;

    bf16x8 bw[8][2];
    load_bw_ws(ws, tid, bw);

    // 128 bf16 rows: row r = row (r&7) of kfront block 16t+(r>>3).
    // ws-mode (l1s=1024) this is a fully contiguous 32KB copy.
    const u16* base = l1 + (size_t)(16 * t) * l1s;
#pragma unroll
    for (int it = 0; it < 8; ++it) {
        int i4 = tid + 256 * it;
        int r = i4 >> 4, c8 = (i4 & 15) << 3;
        uint4 v = *(const uint4*)(base + (size_t)(r >> 3) * l1s + (r & 7) * 128 + c8);
        *(uint4*)(H0 + r * 136 + swz(r, c8)) = v;
    }
    const float2 blp = *(const float2*)(bl + c0);
    const float2 brp = *(const float2*)(br + c0);
    const float bs0 = (blp.x + brp.x) * TANH_S, bs1 = (blp.y + brp.y) * TANH_S;
    __syncthreads();

    // 7 levels {64..1}; 1 bf16 row -> l2 row t
    level_chain<64, 1, true>(H0, H1, bw, bs0, bs1,
                             l2 + (size_t)t * l2s, nullptr, quad, lq, c0);
}

// ---- ktail: 128 rows -> levels 12..18 -> root fp32 -------------------------
__global__ __launch_bounds__(256) void ktail(
    const u16* l2, size_t l2s, const float* __restrict__ bl,
    const float* __restrict__ br, const u16* __restrict__ ws,
    float* __restrict__ out) {
    __shared__ __align__(16) u16 H0[128 * 136];   // 34816 B
    __shared__ __align__(16) u16 H1[64 * 136];    // 17408 B

    const int tid = threadIdx.x;
    const int w = tid >> 6, lane = tid & 63, quad = lane >> 4, lq = lane & 15;
    const int c0 = 32 * w + 2 * lq;

    bf16x8 bw[8][2];
    load_bw_ws(ws, tid, bw);

    // 128 bf16 rows: row r at l2 + r*l2s (ws-mode: contiguous 32KB)
#pragma unroll
    for (int it = 0; it < 8; ++it) {
        int i4 = tid + 256 * it;
        int r = i4 >> 4, c8 = (i4 & 15) << 3;
        uint4 v = *(const uint4*)(l2 + (size_t)r * l2s + c8);
        *(uint4*)(H0 + r * 136 + swz(r, c8)) = v;
    }
    const float2 blp = *(const float2*)(bl + c0);
    const float2 brp = *(const float2*)(br + c0);
    const float bs0 = (blp.x + brp.x) * TANH_S, bs1 = (blp.y + brp.y) * TANH_S;
    __syncthreads();

    // 7 levels {64..1} -> root fp32[128]
    level_chain<64, 1, false>(H0, H1, bw, bs0, bs1, nullptr, out,
                              quad, lq, c0);
}

// ---- host ------------------------------------------------------------------
extern "C" void kernel_launch(void* const* d_in, const int* in_sizes, int n_in,
                              void* d_out, int out_size, void* d_ws, size_t ws_size,
                              hipStream_t stream) {
    float* XB = (float*)d_in[0];
    const float* Win = (const float*)d_in[1];
    const float* bin = (const float*)d_in[2];
    const float* Wl  = (const float*)d_in[3];
    const float* bl  = (const float*)d_in[4];
    const float* Wr  = (const float*)d_in[5];
    const float* br  = (const float*)d_in[6];
    float* out = (float*)d_out;
    u16* ws = (u16*)d_ws;                     // frags always at ws[0..80KB)

    const bool big = (d_ws != nullptr) && (ws_size >= (size_t)WS_NEED);
    u16* l1; int l1s; u16* l2; size_t l2s;
    if (big) {
        // XB read-only; intermediates contiguous in d_ws.
        l1 = (u16*)((char*)d_ws + WS_L1_BYTE); l1s = 1024;   // 8 rows x 128
        l2 = (u16*)((char*)d_ws + WS_L2_BYTE); l2s = 128;
    } else {
        // fallback (R13-proven scheme): consumed XB regions as scratch.
        l1 = (u16*)XB;        l1s = 16384;    // region = 16384 u16
        l2 = (u16*)XB + 8192; l2s = 16 * 16384;  // dead zone of region 16t
    }

    kprep<<<5, 256, 0, stream>>>(Win, Wl, Wr, ws);
    kfront<<<2048, 256, 0, stream>>>(XB, bin, bl, br, ws, l1, l1s);
    kmid<<<128, 256, 0, stream>>>(l1, l1s, bl, br, ws, l2, l2s);
    ktail<<<1, 256, 0, stream>>>(l2, l2s, bl, br, ws, out);
}